// Round 3
// baseline (234.030 us; speedup 1.0000x reference)
//
#include <hip/hip_runtime.h>
#include <cstdint>

typedef _Float16 f16x8 __attribute__((ext_vector_type(8)));
typedef _Float16 f16x4 __attribute__((ext_vector_type(4)));
typedef float    f32x4 __attribute__((ext_vector_type(4)));

static constexpr int TB = 2;
static constexpr int TT = 2048;
static constexpr int TE = 768;
static constexpr int TH = 12;
static constexpr int TD = 64;
static constexpr int TM = TB * TT;      // 4096 rows (B*T)
static constexpr int TK = TE;           // 768 (K for both GEMMs)
static constexpr int NQKV = 3 * TE;     // 2304

#define SCALE_LOG2E 0.18033688011112042f  /* (1/sqrt(64)) * log2(e) */

// async global->LDS, 16B per lane. LDS dest is wave-uniform base + lane*16.
__device__ __forceinline__ void gload16(const void* g, void* lds) {
  __builtin_amdgcn_global_load_lds(
      (__attribute__((address_space(1))) void*)(uintptr_t)g,
      (__attribute__((address_space(3))) void*)(uint32_t)(uintptr_t)lds, 16, 0, 0);
}

// ---------------------------------------------------------------------------
// f32 -> f16 convert for x, w_qkv, w_final (4 elems/thread)
// ---------------------------------------------------------------------------
__global__ void cvt3(const float* __restrict__ x, const float* __restrict__ wq,
                     const float* __restrict__ wf, _Float16* __restrict__ xh,
                     _Float16* __restrict__ wqh, _Float16* __restrict__ wfh) {
  const int NX = TM * TK / 4, NW = NQKV * TK / 4;
  int i = blockIdx.x * 256 + threadIdx.x;
  const float4* src; _Float16* dst; int j;
  if (i < NX)            { src = (const float4*)x;  dst = xh;  j = i; }
  else if (i < NX + NW)  { src = (const float4*)wq; dst = wqh; j = i - NX; }
  else                   { src = (const float4*)wf; dst = wfh; j = i - NX - NW; }
  float4 v = src[j];
  f16x4 o = {(_Float16)v.x, (_Float16)v.y, (_Float16)v.z, (_Float16)v.w};
  *(f16x4*)&dst[(size_t)j * 4] = o;
}

// ---------------------------------------------------------------------------
// NT GEMM: C[M,N] = A[M,K] * Bw[N,K]^T (+bias). 128x128 tile, BK=64, 4 waves.
// EPI=0: qkv epilogue (scatter Q scaled, K, V^T).  EPI=1: plain f32 out.
// ---------------------------------------------------------------------------
template <int EPI>
__global__ __launch_bounds__(256)
void gemm_nt(const _Float16* __restrict__ A, const _Float16* __restrict__ Bw,
             const float* __restrict__ bias,
             _Float16* __restrict__ qb, _Float16* __restrict__ kb,
             _Float16* __restrict__ vtb, float* __restrict__ outp) {
  __shared__ _Float16 As[128 * 64];
  __shared__ _Float16 Bs[128 * 64];
  const int tid = threadIdx.x;
  const int w = tid >> 6, lane = tid & 63;
  const int lr = lane & 15, lk = lane >> 4;
  const int m0 = blockIdx.y * 128, n0 = blockIdx.x * 128;
  const int wr = w >> 1, wc = w & 1;

  f32x4 acc[4][4] = {};
  const char* Ab = (const char*)(A + (size_t)m0 * TK);
  const char* Bb = (const char*)(Bw + (size_t)n0 * TK);

  for (int k0 = 0; k0 < TK; k0 += 64) {
#pragma unroll
    for (int c = 0; c < 4; ++c) {  // A tile: 128 rows x 128B
      int o = (w * 4 + c) * 1024 + lane * 16;
      int row = o >> 7, ch = (o >> 4) & 7;
      gload16(Ab + (size_t)row * (TK * 2) + k0 * 2 + ((ch ^ (row & 7)) << 4),
              (char*)As + (w * 4 + c) * 1024);
    }
#pragma unroll
    for (int c = 0; c < 4; ++c) {  // B tile
      int o = (w * 4 + c) * 1024 + lane * 16;
      int row = o >> 7, ch = (o >> 4) & 7;
      gload16(Bb + (size_t)row * (TK * 2) + k0 * 2 + ((ch ^ (row & 7)) << 4),
              (char*)Bs + (w * 4 + c) * 1024);
    }
    asm volatile("s_waitcnt vmcnt(0)" ::: "memory");
    __syncthreads();

#pragma unroll
    for (int kc = 0; kc < 2; ++kc) {
      f16x8 af[4], bf[4];
#pragma unroll
      for (int mi = 0; mi < 4; ++mi) {
        int row = wr * 64 + mi * 16 + lr;
        af[mi] = *(const f16x8*)&As[row * 64 + (((kc * 4 + lk) ^ (row & 7)) << 3)];
      }
#pragma unroll
      for (int ni = 0; ni < 4; ++ni) {
        int row = wc * 64 + ni * 16 + lr;
        bf[ni] = *(const f16x8*)&Bs[row * 64 + (((kc * 4 + lk) ^ (row & 7)) << 3)];
      }
      __builtin_amdgcn_s_setprio(1);
#pragma unroll
      for (int mi = 0; mi < 4; ++mi)
#pragma unroll
        for (int ni = 0; ni < 4; ++ni)
          acc[mi][ni] = __builtin_amdgcn_mfma_f32_16x16x32_f16(af[mi], bf[ni],
                                                               acc[mi][ni], 0, 0, 0);
      __builtin_amdgcn_s_setprio(0);
    }
    __syncthreads();
  }

  // epilogue: C layout col = lane&15, row = (lane>>4)*4 + r  [m89]
#pragma unroll
  for (int mi = 0; mi < 4; ++mi) {
#pragma unroll
    for (int ni = 0; ni < 4; ++ni) {
      const int col = n0 + wc * 64 + ni * 16 + lr;
#pragma unroll
      for (int r = 0; r < 4; ++r) {
        const int row = m0 + wr * 64 + mi * 16 + lk * 4 + r;
        float v = acc[mi][ni][r];
        if (EPI == 0) {
          v += bias[col];
          const int which = (col >= 2 * TE) ? 2 : (col >= TE ? 1 : 0);
          const int e = col - which * TE;
          const int h = e >> 6, d = e & 63;
          const int b = row >> 11, t = row & (TT - 1);
          const size_t hb = (size_t)(b * TH + h);
          if (which == 0)
            qb[(hb * TT + t) * TD + d] = (_Float16)(v * SCALE_LOG2E);
          else if (which == 1)
            kb[(hb * TT + t) * TD + d] = (_Float16)v;
          else
            vtb[(hb * TD + d) * TT + t] = (_Float16)v;  // V stored transposed
        } else {
          outp[(size_t)row * TE + col] = v;
        }
      }
    }
  }
}

// ---------------------------------------------------------------------------
// Causal flash attention, barrier-free. Grid: 768 blocks, custom mapping:
//   xcd = id&7 owns heads {xcd, xcd+8, xcd+16} (KV stays in one XCD's L2),
//   q-tiles descend (heavy first). 4 waves/block, each wave = 16 q-rows,
//   fully independent: K,V fragments loaded global->VGPR (L2-resident, D=64
//   -> 32 VGPR per operand, time-shared), P via wave-PRIVATE LDS slice.
//   No __syncthreads anywhere; TLP (4 waves/SIMD) hides load latency.
// ---------------------------------------------------------------------------
__global__ __launch_bounds__(256)
void attn_kernel(const _Float16* __restrict__ qbuf, const _Float16* __restrict__ kbuf,
                 const _Float16* __restrict__ vtbuf, _Float16* __restrict__ ob) {
  __shared__ _Float16 Ps[4][16 * 64];
  const int tid = threadIdx.x, w = tid >> 6, lane = tid & 63;
  const int lr = lane & 15, lk = lane >> 4;

  const int id = blockIdx.x;                  // 0..767
  const int xcd = id & 7, j = id >> 3;        // j: 0..95
  const int bh = xcd + 8 * (j >> 5);          // 3 heads per XCD slice
  const int qt = 31 - (j & 31);               // heavy q-tiles first
  const int t0 = qt * 64;

  const size_t hoff = (size_t)bh * (TT * TD);
  const _Float16* q = qbuf + hoff;    // [T][64]
  const _Float16* k = kbuf + hoff;    // [T][64]
  const _Float16* vt = vtbuf + hoff;  // [64][T]
  _Float16* Pw = Ps[w];
  const int rb = w * 16;

  f16x8 qf[2];
#pragma unroll
  for (int kc = 0; kc < 2; ++kc)
    qf[kc] = *(const f16x8*)&q[(size_t)(t0 + rb + lr) * TD + kc * 32 + lk * 8];

  f32x4 of[4] = {};
  float mrun[4], lrun[4];
#pragma unroll
  for (int r = 0; r < 4; ++r) { mrun[r] = -1e30f; lrun[r] = 0.f; }

  const int nt = qt + 1;
  for (int st = 0; st < nt; ++st) {
    const int s0 = st * 64;

    // K fragments straight from global (L2): full 64x64 tile per wave.
    f16x8 kf[2][4];
#pragma unroll
    for (int kc = 0; kc < 2; ++kc)
#pragma unroll
      for (int ni = 0; ni < 4; ++ni)
        kf[kc][ni] =
            *(const f16x8*)&k[(size_t)(s0 + ni * 16 + lr) * TD + kc * 32 + lk * 8];

    // S = Q K^T (already in log2 units)
    f32x4 sa[4] = {};
    __builtin_amdgcn_s_setprio(1);
#pragma unroll
    for (int kc = 0; kc < 2; ++kc)
#pragma unroll
      for (int ni = 0; ni < 4; ++ni)
        sa[ni] =
            __builtin_amdgcn_mfma_f32_16x16x32_f16(qf[kc], kf[kc][ni], sa[ni], 0, 0, 0);
    __builtin_amdgcn_s_setprio(0);

    // V^T fragments issued now; latency hides under softmax. K regs retire.
    f16x8 vf[2][4];
#pragma unroll
    for (int kc = 0; kc < 2; ++kc)
#pragma unroll
      for (int nd = 0; nd < 4; ++nd)
        vf[kc][nd] = *(const f16x8*)&vt[(size_t)(nd * 16 + lr) * TT + s0 +
                                        kc * 32 + lk * 8];

    if (st == nt - 1) {  // diagonal tile: causal mask
#pragma unroll
      for (int ni = 0; ni < 4; ++ni)
#pragma unroll
        for (int r = 0; r < 4; ++r)
          if (s0 + ni * 16 + lr > t0 + rb + lk * 4 + r) sa[ni][r] = -1e30f;
    }

    // wave-parallel row max over the 16 lanes sharing a row
    float mx[4];
#pragma unroll
    for (int r = 0; r < 4; ++r)
      mx[r] = fmaxf(fmaxf(sa[0][r], sa[1][r]), fmaxf(sa[2][r], sa[3][r]));
#pragma unroll
    for (int off = 1; off < 16; off <<= 1)
#pragma unroll
      for (int r = 0; r < 4; ++r) mx[r] = fmaxf(mx[r], __shfl_xor(mx[r], off));

    float al[4], rs[4];
#pragma unroll
    for (int r = 0; r < 4; ++r) {
      float mn = fmaxf(mrun[r], mx[r]);
      al[r] = __builtin_amdgcn_exp2f(mrun[r] - mn);
      mrun[r] = mn;
      rs[r] = 0.f;
    }
#pragma unroll
    for (int ni = 0; ni < 4; ++ni) {
#pragma unroll
      for (int r = 0; r < 4; ++r) {
        float p = __builtin_amdgcn_exp2f(sa[ni][r] - mrun[r]);
        rs[r] += p;
        int row = lk * 4 + r;  // P element (row, col=ni*16+lr), swizzled store
        Pw[row * 64 + (((ni * 2 + (lr >> 3)) ^ (row & 7)) << 3) + (lr & 7)] =
            (_Float16)p;
      }
    }
#pragma unroll
    for (int off = 1; off < 16; off <<= 1)
#pragma unroll
      for (int r = 0; r < 4; ++r) rs[r] += __shfl_xor(rs[r], off);
#pragma unroll
    for (int r = 0; r < 4; ++r) lrun[r] = lrun[r] * al[r] + rs[r];
#pragma unroll
    for (int nd = 0; nd < 4; ++nd)
#pragma unroll
      for (int r = 0; r < 4; ++r) of[nd][r] *= al[r];

    // O += P V  (A = P from wave-private LDS; B = V^T regs). lgkm dep is
    // wave-local; compiler inserts the waitcnt for the Pw write->read.
    __builtin_amdgcn_s_setprio(1);
#pragma unroll
    for (int kc = 0; kc < 2; ++kc) {
      f16x8 pa = *(const f16x8*)&Pw[lr * 64 + (((kc * 4 + lk) ^ (lr & 7)) << 3)];
#pragma unroll
      for (int nd = 0; nd < 4; ++nd)
        of[nd] =
            __builtin_amdgcn_mfma_f32_16x16x32_f16(pa, vf[kc][nd], of[nd], 0, 0, 0);
    }
    __builtin_amdgcn_s_setprio(0);
  }

  const int b = bh / TH, h = bh - b * TH;
#pragma unroll
  for (int nd = 0; nd < 4; ++nd) {
#pragma unroll
    for (int r = 0; r < 4; ++r) {
      int tg = t0 + rb + lk * 4 + r;
      int d = nd * 16 + lr;
      ob[(size_t)(b * TT + tg) * TE + h * TD + d] = (_Float16)(of[nd][r] / lrun[r]);
    }
  }
}

// ---------------------------------------------------------------------------
extern "C" void kernel_launch(void* const* d_in, const int* in_sizes, int n_in,
                              void* d_out, int out_size, void* d_ws, size_t ws_size,
                              hipStream_t stream) {
  const float* x    = (const float*)d_in[0];
  const float* wqkv = (const float*)d_in[1];
  const float* bqkv = (const float*)d_in[2];
  const float* wfin = (const float*)d_in[3];
  float* out = (float*)d_out;

  _Float16* xh  = (_Float16*)d_ws;          // [4096][768]
  _Float16* wqh = xh + (size_t)TM * TK;     // [2304][768]
  _Float16* wfh = wqh + (size_t)NQKV * TK;  // [768][768]
  _Float16* qb  = wfh + (size_t)TE * TE;    // [B,H,T,D] (pre-scaled)
  _Float16* kb  = qb + (size_t)TM * TE;     // [B,H,T,D]
  _Float16* vtb = kb + (size_t)TM * TE;     // [B,H,D,T]
  _Float16* ob  = vtb + (size_t)TM * TE;    // [4096][768] attn output

  cvt3<<<5376, 256, 0, stream>>>(x, wqkv, wfin, xh, wqh, wfh);
  gemm_nt<0><<<dim3(NQKV / 128, TM / 128), 256, 0, stream>>>(
      xh, wqh, bqkv, qb, kb, vtb, nullptr);
  attn_kernel<<<dim3(TT / 64 * TB * TH), 256, 0, stream>>>(qb, kb, vtb, ob);
  gemm_nt<1><<<dim3(TE / 128, TM / 128), 256, 0, stream>>>(
      ob, wfh, nullptr, nullptr, nullptr, nullptr, out);
}

// Round 4
// 118.198 us; speedup vs baseline: 1.9800x; 1.9800x over previous
//
#include <hip/hip_runtime.h>
#include <cstdint>

typedef _Float16 f16x8 __attribute__((ext_vector_type(8)));
typedef _Float16 f16x4 __attribute__((ext_vector_type(4)));
typedef float    f32x4 __attribute__((ext_vector_type(4)));

static constexpr int TB = 2;
static constexpr int TT = 2048;
static constexpr int TE = 768;
static constexpr int TH = 12;
static constexpr int TD = 64;
static constexpr int TM = TB * TT;      // 4096 rows (B*T)
static constexpr int TK = TE;           // 768 (K for both GEMMs)
static constexpr int NQKV = 3 * TE;     // 2304

#define SCALE_LOG2E 0.18033688011112042f  /* (1/sqrt(64)) * log2(e) */

// async global->LDS, 16B per lane. LDS dest is wave-uniform base + lane*16.
__device__ __forceinline__ void gload16(const void* g, void* lds) {
  __builtin_amdgcn_global_load_lds(
      (__attribute__((address_space(1))) void*)(uintptr_t)g,
      (__attribute__((address_space(3))) void*)(uint32_t)(uintptr_t)lds, 16, 0, 0);
}

// ---------------------------------------------------------------------------
// f32 -> f16 convert for x, w_qkv, w_final (4 elems/thread)
// ---------------------------------------------------------------------------
__global__ void cvt3(const float* __restrict__ x, const float* __restrict__ wq,
                     const float* __restrict__ wf, _Float16* __restrict__ xh,
                     _Float16* __restrict__ wqh, _Float16* __restrict__ wfh) {
  const int NX = TM * TK / 4, NW = NQKV * TK / 4;
  int i = blockIdx.x * 256 + threadIdx.x;
  const float4* src; _Float16* dst; int j;
  if (i < NX)            { src = (const float4*)x;  dst = xh;  j = i; }
  else if (i < NX + NW)  { src = (const float4*)wq; dst = wqh; j = i - NX; }
  else                   { src = (const float4*)wf; dst = wfh; j = i - NX - NW; }
  float4 v = src[j];
  f16x4 o = {(_Float16)v.x, (_Float16)v.y, (_Float16)v.z, (_Float16)v.w};
  *(f16x4*)&dst[(size_t)j * 4] = o;
}

// ---------------------------------------------------------------------------
// NT GEMM: C[M,N] = A[M,K] * Bw[N,K]^T (+bias). 128x128 tile, BK=64, 4 waves.
// EPI=0: qkv epilogue (scatter Q scaled, K, V^T).  EPI=1: plain f32 out.
// ---------------------------------------------------------------------------
template <int EPI>
__global__ __launch_bounds__(256)
void gemm_nt(const _Float16* __restrict__ A, const _Float16* __restrict__ Bw,
             const float* __restrict__ bias,
             _Float16* __restrict__ qb, _Float16* __restrict__ kb,
             _Float16* __restrict__ vtb, float* __restrict__ outp) {
  __shared__ _Float16 As[128 * 64];
  __shared__ _Float16 Bs[128 * 64];
  const int tid = threadIdx.x;
  const int w = tid >> 6, lane = tid & 63;
  const int lr = lane & 15, lk = lane >> 4;
  const int m0 = blockIdx.y * 128, n0 = blockIdx.x * 128;
  const int wr = w >> 1, wc = w & 1;

  f32x4 acc[4][4] = {};
  const char* Ab = (const char*)(A + (size_t)m0 * TK);
  const char* Bb = (const char*)(Bw + (size_t)n0 * TK);

  for (int k0 = 0; k0 < TK; k0 += 64) {
#pragma unroll
    for (int c = 0; c < 4; ++c) {  // A tile: 128 rows x 128B
      int o = (w * 4 + c) * 1024 + lane * 16;
      int row = o >> 7, ch = (o >> 4) & 7;
      gload16(Ab + (size_t)row * (TK * 2) + k0 * 2 + ((ch ^ (row & 7)) << 4),
              (char*)As + (w * 4 + c) * 1024);
    }
#pragma unroll
    for (int c = 0; c < 4; ++c) {  // B tile
      int o = (w * 4 + c) * 1024 + lane * 16;
      int row = o >> 7, ch = (o >> 4) & 7;
      gload16(Bb + (size_t)row * (TK * 2) + k0 * 2 + ((ch ^ (row & 7)) << 4),
              (char*)Bs + (w * 4 + c) * 1024);
    }
    asm volatile("s_waitcnt vmcnt(0)" ::: "memory");
    __syncthreads();

#pragma unroll
    for (int kc = 0; kc < 2; ++kc) {
      f16x8 af[4], bf[4];
#pragma unroll
      for (int mi = 0; mi < 4; ++mi) {
        int row = wr * 64 + mi * 16 + lr;
        af[mi] = *(const f16x8*)&As[row * 64 + (((kc * 4 + lk) ^ (row & 7)) << 3)];
      }
#pragma unroll
      for (int ni = 0; ni < 4; ++ni) {
        int row = wc * 64 + ni * 16 + lr;
        bf[ni] = *(const f16x8*)&Bs[row * 64 + (((kc * 4 + lk) ^ (row & 7)) << 3)];
      }
      __builtin_amdgcn_s_setprio(1);
#pragma unroll
      for (int mi = 0; mi < 4; ++mi)
#pragma unroll
        for (int ni = 0; ni < 4; ++ni)
          acc[mi][ni] = __builtin_amdgcn_mfma_f32_16x16x32_f16(af[mi], bf[ni],
                                                               acc[mi][ni], 0, 0, 0);
      __builtin_amdgcn_s_setprio(0);
    }
    __syncthreads();
  }

  // epilogue: C layout col = lane&15, row = (lane>>4)*4 + r  [m89]
#pragma unroll
  for (int mi = 0; mi < 4; ++mi) {
#pragma unroll
    for (int ni = 0; ni < 4; ++ni) {
      const int col = n0 + wc * 64 + ni * 16 + lr;
#pragma unroll
      for (int r = 0; r < 4; ++r) {
        const int row = m0 + wr * 64 + mi * 16 + lk * 4 + r;
        float v = acc[mi][ni][r];
        if (EPI == 0) {
          v += bias[col];
          const int which = (col >= 2 * TE) ? 2 : (col >= TE ? 1 : 0);
          const int e = col - which * TE;
          const int h = e >> 6, d = e & 63;
          const int b = row >> 11, t = row & (TT - 1);
          const size_t hb = (size_t)(b * TH + h);
          if (which == 0)
            qb[(hb * TT + t) * TD + d] = (_Float16)(v * SCALE_LOG2E);
          else if (which == 1)
            kb[(hb * TT + t) * TD + d] = (_Float16)v;
          else
            vtb[(hb * TD + d) * TT + t] = (_Float16)v;  // V stored transposed
        } else {
          outp[(size_t)row * TE + col] = v;
        }
      }
    }
  }
}

// ---------------------------------------------------------------------------
// Causal flash attention. Grid (T/64, B*H). 4 waves; wave w owns 16 q-rows.
// R1 staging pipeline (gload16 dbuf, counted vmcnt, raw s_barrier) +
// SWAPPED QK^T: sa[ni] = mfma(K,Q) -> each lane holds 16 P-values of ONE
// q-row (q = lane&15): softmax is lane-local, P never touches LDS.
// PV uses a permuted-k assignment sigma(lk,j) shared by BOTH operands:
//   A'=P straight from registers, B'=V^T via two swizzled ds_read_b64.
// T13 defer-max (thr=8 in log2 domain) skips O-rescale on most tiles.
// ---------------------------------------------------------------------------
__global__ __launch_bounds__(256)
void attn_kernel(const _Float16* __restrict__ qbuf, const _Float16* __restrict__ kbuf,
                 const _Float16* __restrict__ vtbuf, _Float16* __restrict__ ob) {
  __shared__ _Float16 Ks[2][64 * 64], Vs[2][64 * 64];
  const int tid = threadIdx.x, w = tid >> 6, lane = tid & 63;
  const int lr = lane & 15, lk = lane >> 4;
  const int t0 = ((int)gridDim.x - 1 - (int)blockIdx.x) * 64;  // heavy blocks first
  const int bh = blockIdx.y;
  const size_t hoff = (size_t)bh * (TT * TD);
  const _Float16* q = qbuf + hoff;    // [T][64] (pre-scaled by SCALE*log2e)
  const _Float16* k = kbuf + hoff;    // [T][64]
  const _Float16* vt = vtbuf + hoff;  // [64][T]
  const int rb = w * 16;

  f16x8 qf[2];  // B-operand: Q[q=t0+rb+lr][kc*32+lk*8 ..]
#pragma unroll
  for (int kc = 0; kc < 2; ++kc)
    qf[kc] = *(const f16x8*)&q[(size_t)(t0 + rb + lr) * TD + kc * 32 + lk * 8];

  f32x4 of[4] = {};               // O[q=lk*4+r][d=nd*16+lr]
  float mrun = -1e30f, lrun = 0.f;  // softmax state for q = lane&15 (x4 replicas)

  const int nt = t0 / 64 + 1;

  auto stage = [&](int st, int buf) {
    const int s0 = st * 64;
#pragma unroll
    for (int c = 0; c < 2; ++c) {
      int o = (w * 2 + c) * 1024 + lane * 16;
      int row = o >> 7, ch = (o >> 4) & 7;
      gload16((const char*)(k + (size_t)s0 * TD) + (size_t)row * 128 +
                  ((ch ^ (row & 7)) << 4),
              (char*)Ks[buf] + (w * 2 + c) * 1024);
      gload16((const char*)(vt + s0) + (size_t)row * (TT * 2) +
                  ((ch ^ (row & 7)) << 4),
              (char*)Vs[buf] + (w * 2 + c) * 1024);
    }
  };

  stage(0, 0);
  for (int st = 0; st < nt; ++st) {
    const int cur = st & 1;
    const int s0 = st * 64;
    if (st + 1 < nt) {
      stage(st + 1, cur ^ 1);  // next tile's 4 loads stay in flight
      asm volatile("s_waitcnt vmcnt(4)" ::: "memory");
    } else {
      asm volatile("s_waitcnt vmcnt(0)" ::: "memory");
    }
    __builtin_amdgcn_s_barrier();

    // S^T tile: sa[ni] = mfma(K, Q): lane holds S[s=s0+ni*16+lk*4+r][q=lr]
    f32x4 sa[4] = {};
    __builtin_amdgcn_s_setprio(1);
#pragma unroll
    for (int kc = 0; kc < 2; ++kc) {
#pragma unroll
      for (int ni = 0; ni < 4; ++ni) {
        int row = ni * 16 + lr;
        f16x8 kf =
            *(const f16x8*)&Ks[cur][row * 64 + (((kc * 4 + lk) ^ (row & 7)) << 3)];
        sa[ni] = __builtin_amdgcn_mfma_f32_16x16x32_f16(kf, qf[kc], sa[ni], 0, 0, 0);
      }
    }
    __builtin_amdgcn_s_setprio(0);

    if (st == nt - 1) {  // diagonal tile: causal mask (s > q)
#pragma unroll
      for (int ni = 0; ni < 4; ++ni)
#pragma unroll
        for (int r = 0; r < 4; ++r)
          if (s0 + ni * 16 + lk * 4 + r > t0 + rb + lr) sa[ni][r] = -1e30f;
    }

    // lane-local row max over 16 values, then reduce over the 4 replica lanes
    float mx;
    {
      float m0_ = fmaxf(fmaxf(sa[0][0], sa[0][1]), fmaxf(sa[0][2], sa[0][3]));
      float m1_ = fmaxf(fmaxf(sa[1][0], sa[1][1]), fmaxf(sa[1][2], sa[1][3]));
      float m2_ = fmaxf(fmaxf(sa[2][0], sa[2][1]), fmaxf(sa[2][2], sa[2][3]));
      float m3_ = fmaxf(fmaxf(sa[3][0], sa[3][1]), fmaxf(sa[3][2], sa[3][3]));
      mx = fmaxf(fmaxf(m0_, m1_), fmaxf(m2_, m3_));
      mx = fmaxf(mx, __shfl_xor(mx, 16));
      mx = fmaxf(mx, __shfl_xor(mx, 32));
    }

    // defer-max: rescale only when the wave sees max growth > 8 (log2 units)
    if (__any(mx > mrun + 8.0f)) {
      float mn = fmaxf(mrun, mx);
      float al = __builtin_amdgcn_exp2f(mrun - mn);
      mrun = mn;
      lrun *= al;
      float al4[4];
#pragma unroll
      for (int r = 0; r < 4; ++r) al4[r] = __shfl(al, lk * 4 + r);
#pragma unroll
      for (int nd = 0; nd < 4; ++nd)
#pragma unroll
        for (int r = 0; r < 4; ++r) of[nd][r] *= al4[r];
    }

    // P = exp2(sa - mrun); pack into PV A-fragments in the sigma order:
    // pa[kc] element (ni&1)*4+r  <->  s = 16*(2kc+(ni&1)) + 4*lk + r
    f16x8 pa[2];
    float rs;
    {
      float rn[4];
#pragma unroll
      for (int ni = 0; ni < 4; ++ni) {
        float p0 = __builtin_amdgcn_exp2f(sa[ni][0] - mrun);
        float p1 = __builtin_amdgcn_exp2f(sa[ni][1] - mrun);
        float p2 = __builtin_amdgcn_exp2f(sa[ni][2] - mrun);
        float p3 = __builtin_amdgcn_exp2f(sa[ni][3] - mrun);
        rn[ni] = (p0 + p1) + (p2 + p3);
        pa[ni >> 1][(ni & 1) * 4 + 0] = (_Float16)p0;
        pa[ni >> 1][(ni & 1) * 4 + 1] = (_Float16)p1;
        pa[ni >> 1][(ni & 1) * 4 + 2] = (_Float16)p2;
        pa[ni >> 1][(ni & 1) * 4 + 3] = (_Float16)p3;
      }
      rs = (rn[0] + rn[1]) + (rn[2] + rn[3]);
      rs += __shfl_xor(rs, 16);
      rs += __shfl_xor(rs, 32);
    }
    lrun += rs;

    // O += P V with permuted k-order: B' slot j reads V^T[d][sigma(lk,j)],
    // sigma = 32kc + 16*(j>=4) + 4lk + (j&3)  -> two swizzled ds_read_b64.
    __builtin_amdgcn_s_setprio(1);
#pragma unroll
    for (int kc = 0; kc < 2; ++kc) {
#pragma unroll
      for (int nd = 0; nd < 4; ++nd) {
        int row = nd * 16 + lr;
        const char* vrow = (const char*)&Vs[cur][row * 64];
        f16x8 vv;
#pragma unroll
        for (int b = 0; b < 2; ++b) {
          int ch = 4 * kc + 2 * b + (lk >> 1);
          int byte = ((ch ^ (row & 7)) << 4) | ((lk & 1) << 3);
          *(f16x4*)((char*)&vv + b * 8) = *(const f16x4*)(vrow + byte);
        }
        of[nd] = __builtin_amdgcn_mfma_f32_16x16x32_f16(pa[kc], vv, of[nd], 0, 0, 0);
      }
    }
    __builtin_amdgcn_s_setprio(0);
    __builtin_amdgcn_s_barrier();  // protect cur buffer before restage
  }

  // epilogue: need lrun for q = lk*4+r (owner lane lr = q)
  float linv[4];
#pragma unroll
  for (int r = 0; r < 4; ++r) linv[r] = __shfl(lrun, lk * 4 + r);
  const int b = bh / TH, h = bh - b * TH;
#pragma unroll
  for (int nd = 0; nd < 4; ++nd) {
#pragma unroll
    for (int r = 0; r < 4; ++r) {
      int tg = t0 + rb + lk * 4 + r;
      int d = nd * 16 + lr;
      ob[(size_t)(b * TT + tg) * TE + h * TD + d] = (_Float16)(of[nd][r] / linv[r]);
    }
  }
}

// ---------------------------------------------------------------------------
extern "C" void kernel_launch(void* const* d_in, const int* in_sizes, int n_in,
                              void* d_out, int out_size, void* d_ws, size_t ws_size,
                              hipStream_t stream) {
  const float* x    = (const float*)d_in[0];
  const float* wqkv = (const float*)d_in[1];
  const float* bqkv = (const float*)d_in[2];
  const float* wfin = (const float*)d_in[3];
  float* out = (float*)d_out;

  _Float16* xh  = (_Float16*)d_ws;          // [4096][768]
  _Float16* wqh = xh + (size_t)TM * TK;     // [2304][768]
  _Float16* wfh = wqh + (size_t)NQKV * TK;  // [768][768]
  _Float16* qb  = wfh + (size_t)TE * TE;    // [B,H,T,D] (pre-scaled)
  _Float16* kb  = qb + (size_t)TM * TE;     // [B,H,T,D]
  _Float16* vtb = kb + (size_t)TM * TE;     // [B,H,D,T]
  _Float16* ob  = vtb + (size_t)TM * TE;    // [4096][768] attn output

  cvt3<<<5376, 256, 0, stream>>>(x, wqkv, wfin, xh, wqh, wfh);
  gemm_nt<0><<<dim3(NQKV / 128, TM / 128), 256, 0, stream>>>(
      xh, wqh, bqkv, qb, kb, vtb, nullptr);
  attn_kernel<<<dim3(TT / 64, TB * TH), 256, 0, stream>>>(qb, kb, vtb, ob);
  gemm_nt<1><<<dim3(TE / 128, TM / 128), 256, 0, stream>>>(
      ob, wfh, nullptr, nullptr, nullptr, nullptr, out);
}

// Round 5
// 111.387 us; speedup vs baseline: 2.1010x; 1.0611x over previous
//
#include <hip/hip_runtime.h>
#include <cstdint>

typedef _Float16 f16x8 __attribute__((ext_vector_type(8)));
typedef _Float16 f16x4 __attribute__((ext_vector_type(4)));
typedef float    f32x4 __attribute__((ext_vector_type(4)));

static constexpr int TB = 2;
static constexpr int TT = 2048;
static constexpr int TE = 768;
static constexpr int TH = 12;
static constexpr int TD = 64;
static constexpr int TM = TB * TT;      // 4096 rows (B*T)
static constexpr int TK = TE;           // 768 (K for both GEMMs)
static constexpr int NQKV = 3 * TE;     // 2304

#define SCALE_LOG2E 0.18033688011112042f  /* (1/sqrt(64)) * log2(e) */

// async global->LDS, 16B per lane. LDS dest is wave-uniform base + lane*16.
__device__ __forceinline__ void gload16(const void* g, void* lds) {
  __builtin_amdgcn_global_load_lds(
      (__attribute__((address_space(1))) void*)(uintptr_t)g,
      (__attribute__((address_space(3))) void*)(uint32_t)(uintptr_t)lds, 16, 0, 0);
}

// ---------------------------------------------------------------------------
// f32 -> f16 convert for x, w_qkv, w_final (4 elems/thread)
// ---------------------------------------------------------------------------
__global__ void cvt3(const float* __restrict__ x, const float* __restrict__ wq,
                     const float* __restrict__ wf, _Float16* __restrict__ xh,
                     _Float16* __restrict__ wqh, _Float16* __restrict__ wfh) {
  const int NX = TM * TK / 4, NW = NQKV * TK / 4;
  int i = blockIdx.x * 256 + threadIdx.x;
  const float4* src; _Float16* dst; int j;
  if (i < NX)            { src = (const float4*)x;  dst = xh;  j = i; }
  else if (i < NX + NW)  { src = (const float4*)wq; dst = wqh; j = i - NX; }
  else                   { src = (const float4*)wf; dst = wfh; j = i - NX - NW; }
  float4 v = src[j];
  f16x4 o = {(_Float16)v.x, (_Float16)v.y, (_Float16)v.z, (_Float16)v.w};
  *(f16x4*)&dst[(size_t)j * 4] = o;
}

// ---------------------------------------------------------------------------
// NT GEMM: C[M,N] = A[M,K] * Bw[N,K]^T (+bias). 128x128 tile, BK=64, 4 waves.
// EPI=0: qkv epilogue (scatter Q scaled, K, V^T with s-permuted layout).
// EPI=1: plain f32 out.
// V^T s-permutation (within each 64-aligned s-block): u={kc,hi,lk,m} bits
// [5][4][3:2][1:0] -> u'={kc,lk,hi,m} so that the PV B-fragment (16B per
// lane, slots j=4*hi+m at s=32kc+16hi+4lk+m) is CONTIGUOUS -> ds_read_b128.
// ---------------------------------------------------------------------------
template <int EPI>
__global__ __launch_bounds__(256)
void gemm_nt(const _Float16* __restrict__ A, const _Float16* __restrict__ Bw,
             const float* __restrict__ bias,
             _Float16* __restrict__ qb, _Float16* __restrict__ kb,
             _Float16* __restrict__ vtb, float* __restrict__ outp) {
  __shared__ _Float16 As[128 * 64];
  __shared__ _Float16 Bs[128 * 64];
  const int tid = threadIdx.x;
  const int w = tid >> 6, lane = tid & 63;
  const int lr = lane & 15, lk = lane >> 4;
  const int m0 = blockIdx.y * 128, n0 = blockIdx.x * 128;
  const int wr = w >> 1, wc = w & 1;

  f32x4 acc[4][4] = {};
  const char* Ab = (const char*)(A + (size_t)m0 * TK);
  const char* Bb = (const char*)(Bw + (size_t)n0 * TK);

  for (int k0 = 0; k0 < TK; k0 += 64) {
#pragma unroll
    for (int c = 0; c < 4; ++c) {  // A tile: 128 rows x 128B
      int o = (w * 4 + c) * 1024 + lane * 16;
      int row = o >> 7, ch = (o >> 4) & 7;
      gload16(Ab + (size_t)row * (TK * 2) + k0 * 2 + ((ch ^ (row & 7)) << 4),
              (char*)As + (w * 4 + c) * 1024);
    }
#pragma unroll
    for (int c = 0; c < 4; ++c) {  // B tile
      int o = (w * 4 + c) * 1024 + lane * 16;
      int row = o >> 7, ch = (o >> 4) & 7;
      gload16(Bb + (size_t)row * (TK * 2) + k0 * 2 + ((ch ^ (row & 7)) << 4),
              (char*)Bs + (w * 4 + c) * 1024);
    }
    asm volatile("s_waitcnt vmcnt(0)" ::: "memory");
    __syncthreads();

#pragma unroll
    for (int kc = 0; kc < 2; ++kc) {
      f16x8 af[4], bf[4];
#pragma unroll
      for (int mi = 0; mi < 4; ++mi) {
        int row = wr * 64 + mi * 16 + lr;
        af[mi] = *(const f16x8*)&As[row * 64 + (((kc * 4 + lk) ^ (row & 7)) << 3)];
      }
#pragma unroll
      for (int ni = 0; ni < 4; ++ni) {
        int row = wc * 64 + ni * 16 + lr;
        bf[ni] = *(const f16x8*)&Bs[row * 64 + (((kc * 4 + lk) ^ (row & 7)) << 3)];
      }
      __builtin_amdgcn_s_setprio(1);
#pragma unroll
      for (int mi = 0; mi < 4; ++mi)
#pragma unroll
        for (int ni = 0; ni < 4; ++ni)
          acc[mi][ni] = __builtin_amdgcn_mfma_f32_16x16x32_f16(af[mi], bf[ni],
                                                               acc[mi][ni], 0, 0, 0);
      __builtin_amdgcn_s_setprio(0);
    }
    __syncthreads();
  }

  // epilogue: C layout col = lane&15, row = (lane>>4)*4 + r  [m89]
#pragma unroll
  for (int mi = 0; mi < 4; ++mi) {
#pragma unroll
    for (int ni = 0; ni < 4; ++ni) {
      const int col = n0 + wc * 64 + ni * 16 + lr;
#pragma unroll
      for (int r = 0; r < 4; ++r) {
        const int row = m0 + wr * 64 + mi * 16 + lk * 4 + r;
        float v = acc[mi][ni][r];
        if (EPI == 0) {
          v += bias[col];
          const int which = (col >= 2 * TE) ? 2 : (col >= TE ? 1 : 0);
          const int e = col - which * TE;
          const int h = e >> 6, d = e & 63;
          const int b = row >> 11, t = row & (TT - 1);
          const size_t hb = (size_t)(b * TH + h);
          if (which == 0)
            qb[(hb * TT + t) * TD + d] = (_Float16)(v * SCALE_LOG2E);
          else if (which == 1)
            kb[(hb * TT + t) * TD + d] = (_Float16)v;
          else {
            // V^T with s-permuted layout within each 64-block
            const int u = t & 63;
            const int up = (u & 0x23) | ((u & 0x0C) << 1) | ((u & 0x10) >> 2);
            const int tp = (t & ~63) | up;
            vtb[(hb * TD + d) * TT + tp] = (_Float16)v;
          }
        } else {
          outp[(size_t)row * TE + col] = v;
        }
      }
    }
  }
}

// ---------------------------------------------------------------------------
// Causal flash attention. Grid 768 = 24 heads x 32 q-tiles, mapped as
//   bh = id % 24, qt = 31 - id/24  -> per-CU work balanced (a CU's blocks
//   {c, c+256, c+512} get qt ~ {31-x, 21-x', 10-x''}), heavy blocks first.
// 4 waves; wave w owns 16 q-rows. Staging pipeline: gload16 dbuf, counted
// vmcnt, raw s_barrier. SWAPPED QK^T (mfma(K,Q)): lane holds 16 P-values of
// one q-row -> lane-local softmax, P never touches LDS. PV: A = P packed in
// sigma order, B = V^T read as ds_read_b128 (s-permuted global layout makes
// the fragment contiguous; chunk = kc*4+lk, K-read-identical, conflict-free).
// T13 defer-max (thr=8, log2 domain).
// ---------------------------------------------------------------------------
__global__ __launch_bounds__(256)
void attn_kernel(const _Float16* __restrict__ qbuf, const _Float16* __restrict__ kbuf,
                 const _Float16* __restrict__ vtbuf, _Float16* __restrict__ ob) {
  __shared__ _Float16 Ks[2][64 * 64], Vs[2][64 * 64];
  const int tid = threadIdx.x, w = tid >> 6, lane = tid & 63;
  const int lr = lane & 15, lk = lane >> 4;

  const int id = blockIdx.x;        // 0..767
  const int bh = id % 24;
  const int qt = 31 - id / 24;      // heavy first, balanced per CU
  const int t0 = qt * 64;

  const size_t hoff = (size_t)bh * (TT * TD);
  const _Float16* q = qbuf + hoff;    // [T][64] (pre-scaled by SCALE*log2e)
  const _Float16* k = kbuf + hoff;    // [T][64]
  const _Float16* vt = vtbuf + hoff;  // [64][T] (s-permuted in 64-blocks)
  const int rb = w * 16;

  f16x8 qf[2];  // B-operand: Q[q=t0+rb+lr][kc*32+lk*8 ..]
#pragma unroll
  for (int kc = 0; kc < 2; ++kc)
    qf[kc] = *(const f16x8*)&q[(size_t)(t0 + rb + lr) * TD + kc * 32 + lk * 8];

  f32x4 of[4] = {};                 // O[q=lk*4+r][d=nd*16+lr]
  float mrun = -1e30f, lrun = 0.f;  // softmax state for q = lane&15 (x4 replicas)

  const int nt = qt + 1;

  auto stage = [&](int st, int buf) {
    const int s0 = st * 64;
#pragma unroll
    for (int c = 0; c < 2; ++c) {
      int o = (w * 2 + c) * 1024 + lane * 16;
      int row = o >> 7, ch = (o >> 4) & 7;
      gload16((const char*)(k + (size_t)s0 * TD) + (size_t)row * 128 +
                  ((ch ^ (row & 7)) << 4),
              (char*)Ks[buf] + (w * 2 + c) * 1024);
      gload16((const char*)(vt + s0) + (size_t)row * (TT * 2) +
                  ((ch ^ (row & 7)) << 4),
              (char*)Vs[buf] + (w * 2 + c) * 1024);
    }
  };

  stage(0, 0);
  for (int st = 0; st < nt; ++st) {
    const int cur = st & 1;
    const int s0 = st * 64;
    if (st + 1 < nt) {
      stage(st + 1, cur ^ 1);  // next tile's 4 loads stay in flight
      asm volatile("s_waitcnt vmcnt(4)" ::: "memory");
    } else {
      asm volatile("s_waitcnt vmcnt(0)" ::: "memory");
    }
    __builtin_amdgcn_s_barrier();

    // S^T tile: sa[ni] = mfma(K, Q): lane holds S[s=s0+ni*16+lk*4+r][q=lr]
    f32x4 sa[4] = {};
    __builtin_amdgcn_s_setprio(1);
#pragma unroll
    for (int kc = 0; kc < 2; ++kc) {
#pragma unroll
      for (int ni = 0; ni < 4; ++ni) {
        int row = ni * 16 + lr;
        f16x8 kf =
            *(const f16x8*)&Ks[cur][row * 64 + (((kc * 4 + lk) ^ (row & 7)) << 3)];
        sa[ni] = __builtin_amdgcn_mfma_f32_16x16x32_f16(kf, qf[kc], sa[ni], 0, 0, 0);
      }
    }
    __builtin_amdgcn_s_setprio(0);

    if (st == nt - 1) {  // diagonal tile: causal mask (s > q)
#pragma unroll
      for (int ni = 0; ni < 4; ++ni)
#pragma unroll
        for (int r = 0; r < 4; ++r)
          if (s0 + ni * 16 + lk * 4 + r > t0 + rb + lr) sa[ni][r] = -1e30f;
    }

    // lane-local row max over 16 values, then reduce over the 4 replica lanes
    float mx;
    {
      float m0_ = fmaxf(fmaxf(sa[0][0], sa[0][1]), fmaxf(sa[0][2], sa[0][3]));
      float m1_ = fmaxf(fmaxf(sa[1][0], sa[1][1]), fmaxf(sa[1][2], sa[1][3]));
      float m2_ = fmaxf(fmaxf(sa[2][0], sa[2][1]), fmaxf(sa[2][2], sa[2][3]));
      float m3_ = fmaxf(fmaxf(sa[3][0], sa[3][1]), fmaxf(sa[3][2], sa[3][3]));
      mx = fmaxf(fmaxf(m0_, m1_), fmaxf(m2_, m3_));
      mx = fmaxf(mx, __shfl_xor(mx, 16));
      mx = fmaxf(mx, __shfl_xor(mx, 32));
    }

    // defer-max: rescale only when the wave sees max growth > 8 (log2 units)
    if (__any(mx > mrun + 8.0f)) {
      float mn = fmaxf(mrun, mx);
      float al = __builtin_amdgcn_exp2f(mrun - mn);
      mrun = mn;
      lrun *= al;
      float al4[4];
#pragma unroll
      for (int r = 0; r < 4; ++r) al4[r] = __shfl(al, lk * 4 + r);
#pragma unroll
      for (int nd = 0; nd < 4; ++nd)
#pragma unroll
        for (int r = 0; r < 4; ++r) of[nd][r] *= al4[r];
    }

    // P = exp2(sa - mrun); pack PV A-fragments: pa[kc] slot 4*hi+m holds
    // P[q=lr][s = 32kc + 16hi + 4lk + m]  (hi = ni&1, m = r)
    f16x8 pa[2];
    float rs;
    {
      float rn[4];
#pragma unroll
      for (int ni = 0; ni < 4; ++ni) {
        float p0 = __builtin_amdgcn_exp2f(sa[ni][0] - mrun);
        float p1 = __builtin_amdgcn_exp2f(sa[ni][1] - mrun);
        float p2 = __builtin_amdgcn_exp2f(sa[ni][2] - mrun);
        float p3 = __builtin_amdgcn_exp2f(sa[ni][3] - mrun);
        rn[ni] = (p0 + p1) + (p2 + p3);
        pa[ni >> 1][(ni & 1) * 4 + 0] = (_Float16)p0;
        pa[ni >> 1][(ni & 1) * 4 + 1] = (_Float16)p1;
        pa[ni >> 1][(ni & 1) * 4 + 2] = (_Float16)p2;
        pa[ni >> 1][(ni & 1) * 4 + 3] = (_Float16)p3;
      }
      rs = (rn[0] + rn[1]) + (rn[2] + rn[3]);
      rs += __shfl_xor(rs, 16);
      rs += __shfl_xor(rs, 32);
    }
    lrun += rs;

    // O += P V: B-fragment is one ds_read_b128 (s-permuted layout), chunk =
    // kc*4+lk -> identical pattern to the K read (conflict-free).
    __builtin_amdgcn_s_setprio(1);
#pragma unroll
    for (int kc = 0; kc < 2; ++kc) {
#pragma unroll
      for (int nd = 0; nd < 4; ++nd) {
        int row = nd * 16 + lr;
        f16x8 vv =
            *(const f16x8*)&Vs[cur][row * 64 + (((kc * 4 + lk) ^ (row & 7)) << 3)];
        of[nd] = __builtin_amdgcn_mfma_f32_16x16x32_f16(pa[kc], vv, of[nd], 0, 0, 0);
      }
    }
    __builtin_amdgcn_s_setprio(0);
    __builtin_amdgcn_s_barrier();  // protect cur buffer before restage
  }

  // epilogue: need lrun for q = lk*4+r (owner lane lr = q)
  float linv[4];
#pragma unroll
  for (int r = 0; r < 4; ++r) linv[r] = __shfl(lrun, lk * 4 + r);
  const int b = bh / TH, h = bh - b * TH;
#pragma unroll
  for (int nd = 0; nd < 4; ++nd) {
#pragma unroll
    for (int r = 0; r < 4; ++r) {
      int tg = t0 + rb + lk * 4 + r;
      int d = nd * 16 + lr;
      ob[(size_t)(b * TT + tg) * TE + h * TD + d] = (_Float16)(of[nd][r] / linv[r]);
    }
  }
}

// ---------------------------------------------------------------------------
extern "C" void kernel_launch(void* const* d_in, const int* in_sizes, int n_in,
                              void* d_out, int out_size, void* d_ws, size_t ws_size,
                              hipStream_t stream) {
  const float* x    = (const float*)d_in[0];
  const float* wqkv = (const float*)d_in[1];
  const float* bqkv = (const float*)d_in[2];
  const float* wfin = (const float*)d_in[3];
  float* out = (float*)d_out;

  _Float16* xh  = (_Float16*)d_ws;          // [4096][768]
  _Float16* wqh = xh + (size_t)TM * TK;     // [2304][768]
  _Float16* wfh = wqh + (size_t)NQKV * TK;  // [768][768]
  _Float16* qb  = wfh + (size_t)TE * TE;    // [B,H,T,D] (pre-scaled)
  _Float16* kb  = qb + (size_t)TM * TE;     // [B,H,T,D]
  _Float16* vtb = kb + (size_t)TM * TE;     // [B,H,D,T] (s-permuted)
  _Float16* ob  = vtb + (size_t)TM * TE;    // [4096][768] attn output

  cvt3<<<5376, 256, 0, stream>>>(x, wqkv, wfin, xh, wqh, wfh);
  gemm_nt<0><<<dim3(NQKV / 128, TM / 128), 256, 0, stream>>>(
      xh, wqh, bqkv, qb, kb, vtb, nullptr);
  attn_kernel<<<dim3(TT / 64 * TB * TH), 256, 0, stream>>>(qb, kb, vtb, ob);
  gemm_nt<1><<<dim3(TE / 128, TM / 128), 256, 0, stream>>>(
      ob, wfh, nullptr, nullptr, nullptr, nullptr, out);
}

// Round 6
// 99.007 us; speedup vs baseline: 2.3638x; 1.1250x over previous
//
#include <hip/hip_runtime.h>
#include <cstdint>

typedef _Float16 f16x8 __attribute__((ext_vector_type(8)));
typedef _Float16 f16x4 __attribute__((ext_vector_type(4)));
typedef float    f32x4 __attribute__((ext_vector_type(4)));

static constexpr int TB = 2;
static constexpr int TT = 2048;
static constexpr int TE = 768;
static constexpr int TH = 12;
static constexpr int TD = 64;
static constexpr int TM = TB * TT;      // 4096 rows (B*T)
static constexpr int TK = TE;           // 768 (K for both GEMMs)
static constexpr int NQKV = 3 * TE;     // 2304

#define SCALE_LOG2E 0.18033688011112042f  /* (1/sqrt(64)) * log2(e) */

// async global->LDS, 16B per lane. LDS dest is wave-uniform base + lane*16.
__device__ __forceinline__ void gload16(const void* g, void* lds) {
  __builtin_amdgcn_global_load_lds(
      (__attribute__((address_space(1))) void*)(uintptr_t)g,
      (__attribute__((address_space(3))) void*)(uint32_t)(uintptr_t)lds, 16, 0, 0);
}

// ---------------------------------------------------------------------------
// f32 -> f16 convert for x, w_qkv, w_final (4 elems/thread)
// ---------------------------------------------------------------------------
__global__ void cvt3(const float* __restrict__ x, const float* __restrict__ wq,
                     const float* __restrict__ wf, _Float16* __restrict__ xh,
                     _Float16* __restrict__ wqh, _Float16* __restrict__ wfh) {
  const int NX = TM * TK / 4, NW = NQKV * TK / 4;
  int i = blockIdx.x * 256 + threadIdx.x;
  const float4* src; _Float16* dst; int j;
  if (i < NX)            { src = (const float4*)x;  dst = xh;  j = i; }
  else if (i < NX + NW)  { src = (const float4*)wq; dst = wqh; j = i - NX; }
  else                   { src = (const float4*)wf; dst = wfh; j = i - NX - NW; }
  float4 v = src[j];
  f16x4 o = {(_Float16)v.x, (_Float16)v.y, (_Float16)v.z, (_Float16)v.w};
  *(f16x4*)&dst[(size_t)j * 4] = o;
}

// ---------------------------------------------------------------------------
// NT GEMM: C[M,N] = A[M,K] * Bw[N,K]^T (+bias). 128x128 tile, BK=64, 4 waves.
// DOUBLE-BUFFERED K-loop (counted vmcnt(8) + raw s_barrier, attn's pattern):
// tile k+1's 8 global_load_lds stay in flight across the barrier while tile
// k computes. XCD-chunked 1-D grid: xcd = id&7 owns 4 contiguous M-panels
// (NYT=32 always), x (N-dim) fastest -> per-XCD L2 working set = B + 1 A-panel.
// EPI=0: qkv epilogue (scatter Q scaled, K, V^T with s-permuted layout).
// EPI=1: plain f32 out.
// ---------------------------------------------------------------------------
template <int EPI, int NXT>
__global__ __launch_bounds__(256)
void gemm_nt(const _Float16* __restrict__ A, const _Float16* __restrict__ Bw,
             const float* __restrict__ bias,
             _Float16* __restrict__ qb, _Float16* __restrict__ kb,
             _Float16* __restrict__ vtb, float* __restrict__ outp) {
  __shared__ _Float16 As[2][128 * 64];
  __shared__ _Float16 Bs[2][128 * 64];
  const int tid = threadIdx.x;
  const int w = tid >> 6, lane = tid & 63;
  const int lr = lane & 15, lk = lane >> 4;

  const int id = blockIdx.x;
  const int xcd = id & 7, j = id >> 3;
  const int m0 = (xcd * 4 + j / NXT) * 128;  // 4 M-panels per XCD
  const int n0 = (j % NXT) * 128;
  const int wr = w >> 1, wc = w & 1;

  f32x4 acc[4][4] = {};
  const char* Ab = (const char*)(A + (size_t)m0 * TK);
  const char* Bb = (const char*)(Bw + (size_t)n0 * TK);

  // stage one 64-wide K-tile (A+B, 8 gload16 per wave)
  auto stage = [&](int k0, int buf) {
#pragma unroll
    for (int c = 0; c < 4; ++c) {  // A tile: 128 rows x 128B
      int o = (w * 4 + c) * 1024 + lane * 16;
      int row = o >> 7, ch = (o >> 4) & 7;
      gload16(Ab + (size_t)row * (TK * 2) + k0 * 2 + ((ch ^ (row & 7)) << 4),
              (char*)As[buf] + (w * 4 + c) * 1024);
    }
#pragma unroll
    for (int c = 0; c < 4; ++c) {  // B tile
      int o = (w * 4 + c) * 1024 + lane * 16;
      int row = o >> 7, ch = (o >> 4) & 7;
      gload16(Bb + (size_t)row * (TK * 2) + k0 * 2 + ((ch ^ (row & 7)) << 4),
              (char*)Bs[buf] + (w * 4 + c) * 1024);
    }
  };

  constexpr int NS = TK / 64;  // 12 K-steps
  stage(0, 0);
  for (int ks = 0; ks < NS; ++ks) {
    const int cur = ks & 1;
    if (ks + 1 < NS) {
      stage((ks + 1) * 64, cur ^ 1);  // next tile's 8 loads stay in flight
      asm volatile("s_waitcnt vmcnt(8)" ::: "memory");  // wait only cur's 8
    } else {
      asm volatile("s_waitcnt vmcnt(0)" ::: "memory");
    }
    __builtin_amdgcn_s_barrier();

#pragma unroll
    for (int kc = 0; kc < 2; ++kc) {
      f16x8 af[4], bf[4];
#pragma unroll
      for (int mi = 0; mi < 4; ++mi) {
        int row = wr * 64 + mi * 16 + lr;
        af[mi] =
            *(const f16x8*)&As[cur][row * 64 + (((kc * 4 + lk) ^ (row & 7)) << 3)];
      }
#pragma unroll
      for (int ni = 0; ni < 4; ++ni) {
        int row = wc * 64 + ni * 16 + lr;
        bf[ni] =
            *(const f16x8*)&Bs[cur][row * 64 + (((kc * 4 + lk) ^ (row & 7)) << 3)];
      }
      __builtin_amdgcn_s_setprio(1);
#pragma unroll
      for (int mi = 0; mi < 4; ++mi)
#pragma unroll
        for (int ni = 0; ni < 4; ++ni)
          acc[mi][ni] = __builtin_amdgcn_mfma_f32_16x16x32_f16(af[mi], bf[ni],
                                                               acc[mi][ni], 0, 0, 0);
      __builtin_amdgcn_s_setprio(0);
    }
    __builtin_amdgcn_s_barrier();  // all reads of cur done before restage
  }

  // epilogue: C layout col = lane&15, row = (lane>>4)*4 + r  [m89]
#pragma unroll
  for (int mi = 0; mi < 4; ++mi) {
#pragma unroll
    for (int ni = 0; ni < 4; ++ni) {
      const int col = n0 + wc * 64 + ni * 16 + lr;
#pragma unroll
      for (int r = 0; r < 4; ++r) {
        const int row = m0 + wr * 64 + mi * 16 + lk * 4 + r;
        float v = acc[mi][ni][r];
        if (EPI == 0) {
          v += bias[col];
          const int which = (col >= 2 * TE) ? 2 : (col >= TE ? 1 : 0);
          const int e = col - which * TE;
          const int h = e >> 6, d = e & 63;
          const int b = row >> 11, t = row & (TT - 1);
          const size_t hb = (size_t)(b * TH + h);
          if (which == 0)
            qb[(hb * TT + t) * TD + d] = (_Float16)(v * SCALE_LOG2E);
          else if (which == 1)
            kb[(hb * TT + t) * TD + d] = (_Float16)v;
          else {
            // V^T with s-permuted layout within each 64-block
            const int u = t & 63;
            const int up = (u & 0x23) | ((u & 0x0C) << 1) | ((u & 0x10) >> 2);
            const int tp = (t & ~63) | up;
            vtb[(hb * TD + d) * TT + tp] = (_Float16)v;
          }
        } else {
          outp[(size_t)row * TE + col] = v;
        }
      }
    }
  }
}

// ---------------------------------------------------------------------------
// Causal flash attention. Grid 768 = 24 heads x 32 q-tiles, mapped as
//   bh = id % 24, qt = 31 - id/24  -> per-CU work balanced, heavy first.
// 4 waves; wave w owns 16 q-rows. Staging pipeline: gload16 dbuf, counted
// vmcnt, raw s_barrier. SWAPPED QK^T (mfma(K,Q)): lane holds 16 P-values of
// one q-row -> lane-local softmax, P never touches LDS. PV: A = P packed in
// sigma order, B = V^T read as ds_read_b128 (s-permuted global layout).
// T13 defer-max (thr=8, log2 domain).
// ---------------------------------------------------------------------------
__global__ __launch_bounds__(256)
void attn_kernel(const _Float16* __restrict__ qbuf, const _Float16* __restrict__ kbuf,
                 const _Float16* __restrict__ vtbuf, _Float16* __restrict__ ob) {
  __shared__ _Float16 Ks[2][64 * 64], Vs[2][64 * 64];
  const int tid = threadIdx.x, w = tid >> 6, lane = tid & 63;
  const int lr = lane & 15, lk = lane >> 4;

  const int id = blockIdx.x;        // 0..767
  const int bh = id % 24;
  const int qt = 31 - id / 24;      // heavy first, balanced per CU
  const int t0 = qt * 64;

  const size_t hoff = (size_t)bh * (TT * TD);
  const _Float16* q = qbuf + hoff;    // [T][64] (pre-scaled by SCALE*log2e)
  const _Float16* k = kbuf + hoff;    // [T][64]
  const _Float16* vt = vtbuf + hoff;  // [64][T] (s-permuted in 64-blocks)
  const int rb = w * 16;

  f16x8 qf[2];  // B-operand: Q[q=t0+rb+lr][kc*32+lk*8 ..]
#pragma unroll
  for (int kc = 0; kc < 2; ++kc)
    qf[kc] = *(const f16x8*)&q[(size_t)(t0 + rb + lr) * TD + kc * 32 + lk * 8];

  f32x4 of[4] = {};                 // O[q=lk*4+r][d=nd*16+lr]
  float mrun = -1e30f, lrun = 0.f;  // softmax state for q = lane&15 (x4 replicas)

  const int nt = qt + 1;

  auto stage = [&](int st, int buf) {
    const int s0 = st * 64;
#pragma unroll
    for (int c = 0; c < 2; ++c) {
      int o = (w * 2 + c) * 1024 + lane * 16;
      int row = o >> 7, ch = (o >> 4) & 7;
      gload16((const char*)(k + (size_t)s0 * TD) + (size_t)row * 128 +
                  ((ch ^ (row & 7)) << 4),
              (char*)Ks[buf] + (w * 2 + c) * 1024);
      gload16((const char*)(vt + s0) + (size_t)row * (TT * 2) +
                  ((ch ^ (row & 7)) << 4),
              (char*)Vs[buf] + (w * 2 + c) * 1024);
    }
  };

  stage(0, 0);
  for (int st = 0; st < nt; ++st) {
    const int cur = st & 1;
    const int s0 = st * 64;
    if (st + 1 < nt) {
      stage(st + 1, cur ^ 1);  // next tile's 4 loads stay in flight
      asm volatile("s_waitcnt vmcnt(4)" ::: "memory");
    } else {
      asm volatile("s_waitcnt vmcnt(0)" ::: "memory");
    }
    __builtin_amdgcn_s_barrier();

    // S^T tile: sa[ni] = mfma(K, Q): lane holds S[s=s0+ni*16+lk*4+r][q=lr]
    f32x4 sa[4] = {};
    __builtin_amdgcn_s_setprio(1);
#pragma unroll
    for (int kc = 0; kc < 2; ++kc) {
#pragma unroll
      for (int ni = 0; ni < 4; ++ni) {
        int row = ni * 16 + lr;
        f16x8 kf =
            *(const f16x8*)&Ks[cur][row * 64 + (((kc * 4 + lk) ^ (row & 7)) << 3)];
        sa[ni] = __builtin_amdgcn_mfma_f32_16x16x32_f16(kf, qf[kc], sa[ni], 0, 0, 0);
      }
    }
    __builtin_amdgcn_s_setprio(0);

    if (st == nt - 1) {  // diagonal tile: causal mask (s > q)
#pragma unroll
      for (int ni = 0; ni < 4; ++ni)
#pragma unroll
        for (int r = 0; r < 4; ++r)
          if (s0 + ni * 16 + lk * 4 + r > t0 + rb + lr) sa[ni][r] = -1e30f;
    }

    // lane-local row max over 16 values, then reduce over the 4 replica lanes
    float mx;
    {
      float m0_ = fmaxf(fmaxf(sa[0][0], sa[0][1]), fmaxf(sa[0][2], sa[0][3]));
      float m1_ = fmaxf(fmaxf(sa[1][0], sa[1][1]), fmaxf(sa[1][2], sa[1][3]));
      float m2_ = fmaxf(fmaxf(sa[2][0], sa[2][1]), fmaxf(sa[2][2], sa[2][3]));
      float m3_ = fmaxf(fmaxf(sa[3][0], sa[3][1]), fmaxf(sa[3][2], sa[3][3]));
      mx = fmaxf(fmaxf(m0_, m1_), fmaxf(m2_, m3_));
      mx = fmaxf(mx, __shfl_xor(mx, 16));
      mx = fmaxf(mx, __shfl_xor(mx, 32));
    }

    // defer-max: rescale only when the wave sees max growth > 8 (log2 units)
    if (__any(mx > mrun + 8.0f)) {
      float mn = fmaxf(mrun, mx);
      float al = __builtin_amdgcn_exp2f(mrun - mn);
      mrun = mn;
      lrun *= al;
      float al4[4];
#pragma unroll
      for (int r = 0; r < 4; ++r) al4[r] = __shfl(al, lk * 4 + r);
#pragma unroll
      for (int nd = 0; nd < 4; ++nd)
#pragma unroll
        for (int r = 0; r < 4; ++r) of[nd][r] *= al4[r];
    }

    // P = exp2(sa - mrun); pack PV A-fragments: pa[kc] slot 4*hi+m holds
    // P[q=lr][s = 32kc + 16hi + 4lk + m]  (hi = ni&1, m = r)
    f16x8 pa[2];
    float rs;
    {
      float rn[4];
#pragma unroll
      for (int ni = 0; ni < 4; ++ni) {
        float p0 = __builtin_amdgcn_exp2f(sa[ni][0] - mrun);
        float p1 = __builtin_amdgcn_exp2f(sa[ni][1] - mrun);
        float p2 = __builtin_amdgcn_exp2f(sa[ni][2] - mrun);
        float p3 = __builtin_amdgcn_exp2f(sa[ni][3] - mrun);
        rn[ni] = (p0 + p1) + (p2 + p3);
        pa[ni >> 1][(ni & 1) * 4 + 0] = (_Float16)p0;
        pa[ni >> 1][(ni & 1) * 4 + 1] = (_Float16)p1;
        pa[ni >> 1][(ni & 1) * 4 + 2] = (_Float16)p2;
        pa[ni >> 1][(ni & 1) * 4 + 3] = (_Float16)p3;
      }
      rs = (rn[0] + rn[1]) + (rn[2] + rn[3]);
      rs += __shfl_xor(rs, 16);
      rs += __shfl_xor(rs, 32);
    }
    lrun += rs;

    // O += P V: B-fragment is one ds_read_b128 (s-permuted layout), chunk =
    // kc*4+lk -> identical pattern to the K read (conflict-free).
    __builtin_amdgcn_s_setprio(1);
#pragma unroll
    for (int kc = 0; kc < 2; ++kc) {
#pragma unroll
      for (int nd = 0; nd < 4; ++nd) {
        int row = nd * 16 + lr;
        f16x8 vv =
            *(const f16x8*)&Vs[cur][row * 64 + (((kc * 4 + lk) ^ (row & 7)) << 3)];
        of[nd] = __builtin_amdgcn_mfma_f32_16x16x32_f16(pa[kc], vv, of[nd], 0, 0, 0);
      }
    }
    __builtin_amdgcn_s_setprio(0);
    __builtin_amdgcn_s_barrier();  // protect cur buffer before restage
  }

  // epilogue: need lrun for q = lk*4+r (owner lane lr = q)
  float linv[4];
#pragma unroll
  for (int r = 0; r < 4; ++r) linv[r] = __shfl(lrun, lk * 4 + r);
  const int b = bh / TH, h = bh - b * TH;
#pragma unroll
  for (int nd = 0; nd < 4; ++nd) {
#pragma unroll
    for (int r = 0; r < 4; ++r) {
      int tg = t0 + rb + lk * 4 + r;
      int d = nd * 16 + lr;
      ob[(size_t)(b * TT + tg) * TE + h * TD + d] = (_Float16)(of[nd][r] / linv[r]);
    }
  }
}

// ---------------------------------------------------------------------------
extern "C" void kernel_launch(void* const* d_in, const int* in_sizes, int n_in,
                              void* d_out, int out_size, void* d_ws, size_t ws_size,
                              hipStream_t stream) {
  const float* x    = (const float*)d_in[0];
  const float* wqkv = (const float*)d_in[1];
  const float* bqkv = (const float*)d_in[2];
  const float* wfin = (const float*)d_in[3];
  float* out = (float*)d_out;

  _Float16* xh  = (_Float16*)d_ws;          // [4096][768]
  _Float16* wqh = xh + (size_t)TM * TK;     // [2304][768]
  _Float16* wfh = wqh + (size_t)NQKV * TK;  // [768][768]
  _Float16* qb  = wfh + (size_t)TE * TE;    // [B,H,T,D] (pre-scaled)
  _Float16* kb  = qb + (size_t)TM * TE;     // [B,H,T,D]
  _Float16* vtb = kb + (size_t)TM * TE;     // [B,H,D,T] (s-permuted)
  _Float16* ob  = vtb + (size_t)TM * TE;    // [4096][768] attn output

  cvt3<<<5376, 256, 0, stream>>>(x, wqkv, wfin, xh, wqh, wfh);
  gemm_nt<0, NQKV / 128><<<(NQKV / 128) * (TM / 128), 256, 0, stream>>>(
      xh, wqh, bqkv, qb, kb, vtb, nullptr);
  attn_kernel<<<dim3(TT / 64 * TB * TH), 256, 0, stream>>>(qb, kb, vtb, ob);
  gemm_nt<1, TE / 128><<<(TE / 128) * (TM / 128), 256, 0, stream>>>(
      ob, wfh, nullptr, nullptr, nullptr, nullptr, out);
}